// Round 6
// baseline (550.911 us; speedup 1.0000x reference)
//
#include <hip/hip_runtime.h>
#include <cfloat>

#define B_SZ   32768
#define IN_D   1024
#define HID    64
#define COMM   256
#define NPROTO 8192

#define SSCALE 12.0f
#define PSCALE 1.0e6f

typedef __attribute__((ext_vector_type(8))) short bf16x8;
typedef __attribute__((ext_vector_type(4))) float f32x4;
typedef __attribute__((ext_vector_type(4))) int   i32x4;

#define AS1 __attribute__((address_space(1)))
#define AS3 __attribute__((address_space(3)))

__device__ __forceinline__ unsigned short f2bf(float f) {
    unsigned u = __float_as_uint(f);
    unsigned r = u + 0x7fff + ((u >> 16) & 1);   // round-to-nearest-even
    return (unsigned short)(r >> 16);
}

__device__ __forceinline__ int f2i8(float f, float scale) {
    float v = fminf(fmaxf(f * scale, -127.f), 127.f);
    return __float2int_rn(v);
}

// ---------------------------------------------------------------------------
// prep_all: blocks [0,106): weight transpose fp32->bf16 W^T, 16B chunk writes.
//           blocks [106,2154): protos -> int8 tiled + pnormS.
// ---------------------------------------------------------------------------
__global__ __launch_bounds__(256) void prep_all(
    const float* __restrict__ Wf,  const float* __restrict__ W0,
    const float* __restrict__ W1,  const float* __restrict__ Wmu,
    const float* __restrict__ Wvar, const float* __restrict__ protos,
    unsigned short* __restrict__ Wft, unsigned short* __restrict__ W0t,
    unsigned short* __restrict__ W1t, unsigned short* __restrict__ Wmt,
    unsigned short* __restrict__ Wvt,
    float* __restrict__ pnormS, char* __restrict__ protoq)
{
    int bid = blockIdx.x;
    if (bid < 106) {
        int gid = bid * 256 + threadIdx.x;          // chunk id, 27136 total
        if (gid >= 27136) return;
        const float* src; unsigned short* dst; int c, K, N;
        if (gid < 8192)       { src = Wf;  dst = Wft; c = gid;          K = 1024; N = 64;  }
        else if (gid < 8704)  { src = W0;  dst = W0t; c = gid - 8192;   K = 64;   N = 64;  }
        else if (gid < 10752) { src = W1;  dst = W1t; c = gid - 8704;   K = 64;   N = 256; }
        else if (gid < 18944) { src = Wmu; dst = Wmt; c = gid - 10752;  K = 256;  N = 256; }
        else                  { src = Wvar;dst = Wvt; c = gid - 18944;  K = 256;  N = 256; }
        int n  = c % N;                              // N is power of 2
        int k0 = (c / N) * 8;
        bf16x8 o;
#pragma unroll
        for (int j = 0; j < 8; ++j) o[j] = (short)f2bf(src[(size_t)(k0 + j) * N + n]);
        *(bf16x8*)(dst + (size_t)n * K + k0) = o;
    } else {
        int g    = (bid - 106) * 256 + threadIdx.x;
        int p    = g >> 6;
        int lane = g & 63;
        float4 v = *(const float4*)&protos[(size_t)p * COMM + lane * 4];
        int b0 = f2i8(v.x, PSCALE) & 0xff;
        int b1 = f2i8(v.y, PSCALE) & 0xff;
        int b2 = f2i8(v.z, PSCALE) & 0xff;
        int b3 = f2i8(v.w, PSCALE) & 0xff;
        int pk = b0 | (b1 << 8) | (b2 << 16) | (b3 << 24);
        int T = p >> 7, jc = lane >> 2;
        *(int*)(protoq + ((size_t)(T * 16 + jc) * 128 + (p & 127)) * 16 + (lane & 3) * 4) = pk;
        float s = v.x * v.x + v.y * v.y + v.z * v.z + v.w * v.w;
#pragma unroll
        for (int off = 32; off; off >>= 1) s += __shfl_down(s, off);
        if (lane == 0) pnormS[p] = s * (SSCALE * PSCALE);
    }
}

// ---------------------------------------------------------------------------
// Fused MLP, 32 rows/block, 40 KB LDS, dbuf (unchanged from round 5).
// ---------------------------------------------------------------------------
__global__ __launch_bounds__(256, 4) void mlp_fused(
    const float* __restrict__ x,
    const unsigned short* __restrict__ Wft, const float* __restrict__ b_feat,
    const unsigned short* __restrict__ W0t, const float* __restrict__ b0,
    const unsigned short* __restrict__ W1t, const float* __restrict__ b1,
    unsigned short* __restrict__ h3b)
{
    __shared__ __align__(16) char lds[40960];
    char* Xs0 = lds;
    char* Xs1 = lds + 8192;
    char* Ws0 = lds + 16384;
    char* Ws1 = lds + 24576;
    char* H1  = lds + 32768;
    char* H2  = lds + 36864;

    const int t   = threadIdx.x;
    const int w   = t >> 6;
    const int l   = t & 63;
    const int q   = l >> 4;
    const int j16 = l & 15;
    const int rh  = w >> 1;
    const int ch  = w & 1;
    const int rowBase = blockIdx.x * 32;
    const int m = rh * 16 + j16;

    auto stageX = [&](int ks, char* dst) {
#pragma unroll
        for (int i = 0; i < 2; ++i) {
            int p  = i * 256 + t;
            int r  = p >> 4;
            int cs = p & 15;
            int j  = cs ^ (r & 15);
            const float* g = x + (size_t)(rowBase + r) * IN_D + ks * 64 + j * 4;
            void* d = dst + (size_t)(i * 256 + w * 64) * 16;
            __builtin_amdgcn_global_load_lds((const AS1 void*)g, (AS3 void*)d, 16, 0, 0);
        }
    };
    auto stageW = [&](const unsigned short* Wt, int ldk, int ks, char* dst) {
#pragma unroll
        for (int i = 0; i < 2; ++i) {
            int p  = i * 256 + t;
            int n  = p >> 3;
            int cs = p & 7;
            int j  = cs ^ (n & 7);
            const unsigned short* g = Wt + (size_t)n * ldk + ks * 64 + j * 8;
            void* d = dst + (size_t)(i * 256 + w * 64) * 16;
            __builtin_amdgcn_global_load_lds((const AS1 void*)g, (AS3 void*)d, 16, 0, 0);
        }
    };
    auto afragX = [&](const char* Xsb, int kk) -> bf16x8 {
        int jc = kk * 8 + q * 2;
        f32x4 a0 = *(const f32x4*)(Xsb + (size_t)(m * 16 + (jc ^ (m & 15))) * 16);
        f32x4 a1 = *(const f32x4*)(Xsb + (size_t)(m * 16 + ((jc + 1) ^ (m & 15))) * 16);
        bf16x8 o;
        o[0] = (short)f2bf(a0[0]); o[1] = (short)f2bf(a0[1]);
        o[2] = (short)f2bf(a0[2]); o[3] = (short)f2bf(a0[3]);
        o[4] = (short)f2bf(a1[0]); o[5] = (short)f2bf(a1[1]);
        o[6] = (short)f2bf(a1[2]); o[7] = (short)f2bf(a1[3]);
        return o;
    };
    auto bfrag = [&](const char* Wsb, int kk, int v) -> bf16x8 {
        int n  = ch * 32 + 16 * v + j16;
        int jc = kk * 4 + q;
        return *(const bf16x8*)(Wsb + (size_t)(n * 8 + (jc ^ (n & 7))) * 16);
    };
    auto afragH = [&](const char* Hs, int kk) -> bf16x8 {
        int jc = kk * 4 + q;
        return *(const bf16x8*)(Hs + (size_t)(m * 8 + (jc ^ (m & 7))) * 16);
    };

    // stage 1
    f32x4 acc1[2];
#pragma unroll
    for (int v = 0; v < 2; ++v) acc1[v] = (f32x4){0.f, 0.f, 0.f, 0.f};
    stageX(0, Xs0);
    stageW(Wft, IN_D, 0, Ws0);
    for (int ks = 0; ks < 16; ++ks) {
        int buf = ks & 1;
        __syncthreads();
        if (ks < 15) {
            stageX(ks + 1, buf ? Xs0 : Xs1);
            stageW(Wft, IN_D, ks + 1, buf ? Ws0 : Ws1);
        }
        const char* Xsb = buf ? Xs1 : Xs0;
        const char* Wsb = buf ? Ws1 : Ws0;
#pragma unroll
        for (int kk = 0; kk < 2; ++kk) {
            bf16x8 af = afragX(Xsb, kk);
#pragma unroll
            for (int v = 0; v < 2; ++v)
                acc1[v] = __builtin_amdgcn_mfma_f32_16x16x32_bf16(
                    af, bfrag(Wsb, kk, v), acc1[v], 0, 0, 0);
        }
    }
#pragma unroll
    for (int v = 0; v < 2; ++v) {
        int c = ch * 32 + 16 * v + j16;
        float bb = b_feat[c];
#pragma unroll
        for (int rg = 0; rg < 4; ++rg) {
            int r = rh * 16 + q * 4 + rg;
            float h = acc1[v][rg] + bb;
            *(short*)(H1 + (size_t)(r * 8 + ((c >> 3) ^ (r & 7))) * 16 + (c & 7) * 2)
                = (short)f2bf(h);
        }
    }
    stageW(W0t, 64, 0, Ws0);
    __syncthreads();

    // stage 2
    f32x4 acc2[2];
#pragma unroll
    for (int v = 0; v < 2; ++v) acc2[v] = (f32x4){0.f, 0.f, 0.f, 0.f};
#pragma unroll
    for (int kk = 0; kk < 2; ++kk) {
        bf16x8 af = afragH(H1, kk);
#pragma unroll
        for (int v = 0; v < 2; ++v)
            acc2[v] = __builtin_amdgcn_mfma_f32_16x16x32_bf16(
                af, bfrag(Ws0, kk, v), acc2[v], 0, 0, 0);
    }
#pragma unroll
    for (int v = 0; v < 2; ++v) {
        int c = ch * 32 + 16 * v + j16;
        float bb = b0[c];
#pragma unroll
        for (int rg = 0; rg < 4; ++rg) {
            int r = rh * 16 + q * 4 + rg;
            float h = fmaxf(acc2[v][rg] + bb, 0.f);
            *(short*)(H2 + (size_t)(r * 8 + ((c >> 3) ^ (r & 7))) * 16 + (c & 7) * 2)
                = (short)f2bf(h);
        }
    }
    stageW(W1t, 64, 0, Ws1);
    __syncthreads();

    // stage 3
    auto stage3 = [&](int c4, const char* Wsb) {
        f32x4 acc[2];
#pragma unroll
        for (int v = 0; v < 2; ++v) acc[v] = (f32x4){0.f, 0.f, 0.f, 0.f};
#pragma unroll
        for (int kk = 0; kk < 2; ++kk) {
            bf16x8 af = afragH(H2, kk);
#pragma unroll
            for (int v = 0; v < 2; ++v)
                acc[v] = __builtin_amdgcn_mfma_f32_16x16x32_bf16(
                    af, bfrag(Wsb, kk, v), acc[v], 0, 0, 0);
        }
#pragma unroll
        for (int v = 0; v < 2; ++v) {
            int col = c4 * 64 + ch * 32 + 16 * v + j16;
            float bb = b1[col];
#pragma unroll
            for (int rg = 0; rg < 4; ++rg) {
                int row = rowBase + rh * 16 + q * 4 + rg;
                float h = fmaxf(acc[v][rg] + bb, 0.f);
                h3b[(size_t)row * COMM + col] = f2bf(h);
            }
        }
    };
    stageW(W1t + (size_t)64 * 64, 64, 0, Ws0);
    stage3(0, Ws1);
    __syncthreads();
    stageW(W1t + (size_t)128 * 64, 64, 0, Ws1);
    stage3(1, Ws0);
    __syncthreads();
    stageW(W1t + (size_t)192 * 64, 64, 0, Ws0);
    stage3(2, Ws1);
    __syncthreads();
    stage3(3, Ws0);
}

// ---------------------------------------------------------------------------
// Head v2: W fragments loaded DIRECT from global (L2-resident, 128 KB each) —
// no W LDS, no k-loop barriers. Only H3 staging uses LDS (16 KB, one barrier).
// ---------------------------------------------------------------------------
__global__ __launch_bounds__(256, 4) void head_mfma(
    const unsigned short* __restrict__ h3b,
    const unsigned short* __restrict__ Wmt, const float* __restrict__ bmu,
    const unsigned short* __restrict__ Wvt, const float* __restrict__ bvar,
    const float* __restrict__ eps,
    float* __restrict__ sample,
    char* __restrict__ sampleq,
    float* __restrict__ klpart)
{
    __shared__ __align__(16) char H3[16384];

    const int t   = threadIdx.x;
    const int w   = t >> 6;
    const int l   = t & 63;
    const int q   = l >> 4;
    const int j16 = l & 15;
    const int rh  = w >> 1;
    const int ch  = w & 1;
    const int rowBase = blockIdx.x * 32;
    const int m = rh * 16 + j16;

    // stage H3: 1024 chunks, 4/thread, 32-chunk-row swizzle
#pragma unroll
    for (int i = 0; i < 4; ++i) {
        int p  = i * 256 + t;
        int r  = p >> 5;
        int js = p & 31;
        int j  = (js & 24) | ((js & 7) ^ (r & 7));
        const unsigned short* g = h3b + (size_t)(rowBase + r) * COMM + j * 8;
        void* d = H3 + (size_t)(i * 256 + w * 64) * 16;
        __builtin_amdgcn_global_load_lds((const AS1 void*)g, (AS3 void*)d, 16, 0, 0);
    }
    __syncthreads();

    float kl = 0.f;
    for (int c = 0; c < 4; ++c) {
        f32x4 am[2], av[2];
#pragma unroll
        for (int v = 0; v < 2; ++v) {
            am[v] = (f32x4){0.f, 0.f, 0.f, 0.f};
            av[v] = (f32x4){0.f, 0.f, 0.f, 0.f};
        }
#pragma unroll 2
        for (int ks = 0; ks < 4; ++ks) {
#pragma unroll
            for (int kk = 0; kk < 2; ++kk) {
                int jwg = ks * 8 + kk * 4 + q;
                bf16x8 af = *(const bf16x8*)(H3 +
                    (size_t)(m * 32 + ((jwg & 24) | ((jwg & 7) ^ (m & 7)))) * 16);
                int koff = ks * 64 + kk * 32 + q * 8;
#pragma unroll
                for (int v = 0; v < 2; ++v) {
                    int n = c * 64 + ch * 32 + 16 * v + j16;
                    bf16x8 bm = *(const bf16x8*)(Wmt + (size_t)n * COMM + koff);
                    bf16x8 bv = *(const bf16x8*)(Wvt + (size_t)n * COMM + koff);
                    am[v] = __builtin_amdgcn_mfma_f32_16x16x32_bf16(af, bm, am[v], 0, 0, 0);
                    av[v] = __builtin_amdgcn_mfma_f32_16x16x32_bf16(af, bv, av[v], 0, 0, 0);
                }
            }
        }
#pragma unroll
        for (int v = 0; v < 2; ++v) {
            int col = c * 64 + ch * 32 + 16 * v + j16;
            float bm_ = bmu[col];
            float bv_ = bvar[col];
#pragma unroll
            for (int rg = 0; rg < 4; ++rg) {
                int row = rowBase + rh * 16 + q * 4 + rg;
                float mu = am[v][rg] + bm_;
                float lv = av[v][rg] + bv_;
                float e  = expf(0.5f * lv);
                float s  = mu + eps[(size_t)row * COMM + col] * e;
                sample [(size_t)row * COMM + col] = s;
                sampleq[(size_t)row * COMM + col] = (char)f2i8(s, SSCALE);
                kl += 1.f + lv - mu * mu - e * e;
            }
        }
    }
#pragma unroll
    for (int off = 32; off; off >>= 1) kl += __shfl_down(kl, off);
    __shared__ float wsum[4];
    if (l == 0) wsum[w] = kl;
    __syncthreads();
    if (t == 0)
        klpart[blockIdx.x] = wsum[0] + wsum[1] + wsum[2] + wsum[3];
}

// ---------------------------------------------------------------------------
// i8 MFMA distance + argmin v3: BARRIER-FREE K-loop.
// A (128x256 i8, 32 KB LDS) staged once; B fragments loaded direct
// global->VGPR (coalesced via tiled protoq), one-slice-ahead reg prefetch.
// No __syncthreads in the hot loop -> no vmcnt(0) drains.
// ---------------------------------------------------------------------------
#define SPLITS 4
#define SPAN   (NPROTO / SPLITS)   // 2048
#define NT     (SPAN / 128)        // 16 proto tiles per block

__global__ __launch_bounds__(256, 3) void vq_argmin_i8(
    const char* __restrict__ sampleq,
    const char* __restrict__ protoq,
    const float* __restrict__ pnormS,
    float* __restrict__ minval,
    int* __restrict__ minidx)
{
    __shared__ __align__(16) char As[32768];

    const int t   = threadIdx.x;
    const int w   = t >> 6;
    const int l   = t & 63;
    const int q   = l >> 4;
    const int j16 = l & 15;
    const int wrow = (w >> 1) * 64;
    const int wcol = (w & 1) * 64;
    const int rowBase = blockIdx.x * 128;
    const int tBase   = blockIdx.y * NT;

    // stage A: 2048 16B chunks, xor-16 swizzle
#pragma unroll
    for (int i = 0; i < 8; ++i) {
        int p  = i * 256 + t;
        int r  = p >> 4;
        int cs = p & 15;
        int j  = cs ^ (r & 15);
        const char* g = sampleq + (size_t)(rowBase + r) * COMM + j * 16;
        void* d = As + (size_t)(i * 256 + w * 64) * 16;
        __builtin_amdgcn_global_load_lds((const AS1 void*)g, (AS3 void*)d, 16, 0, 0);
    }
    __syncthreads();

    // this wave's B base: tile stride 32768 B, ks stride 8192 B, v stride 256 B
    const char* bbase = protoq + ((size_t)(tBase * 16 + q) * 128 + wcol + j16) * 16;

    float bestv[16];
    int   besti[16];
#pragma unroll
    for (int s = 0; s < 16; ++s) { bestv[s] = FLT_MAX; besti[s] = 0; }

    // prefetch slice (pt=0, ks=0)
    i32x4 bfv[4], bnx[4];
#pragma unroll
    for (int v = 0; v < 4; ++v)
        bfv[v] = *(const i32x4*)(bbase + v * 256);

    for (int pt = 0; pt < NT; ++pt) {
        i32x4 acc[4][4];
#pragma unroll
        for (int u = 0; u < 4; ++u)
#pragma unroll
            for (int v = 0; v < 4; ++v) acc[u][v] = (i32x4){0, 0, 0, 0};

#pragma unroll
        for (int ks = 0; ks < 4; ++ks) {
            // prefetch next slice's B into bnx (no barrier anywhere)
            int nid = pt * 4 + ks + 1;
            if (nid < NT * 4) {
                const char* nb = bbase + (size_t)nid * 8192;
#pragma unroll
                for (int v = 0; v < 4; ++v)
                    bnx[v] = *(const i32x4*)(nb + v * 256);
            }
            // A fragments from LDS (no barrier needed: written once)
            i32x4 af[4];
            int jc = ks * 4 + q;
#pragma unroll
            for (int u = 0; u < 4; ++u) {
                int mm = wrow + 16 * u + j16;
                af[u] = *(const i32x4*)(As + (size_t)(mm * 16 + (jc ^ (mm & 15))) * 16);
            }
#pragma unroll
            for (int u = 0; u < 4; ++u)
#pragma unroll
                for (int v = 0; v < 4; ++v)
                    acc[u][v] = __builtin_amdgcn_mfma_i32_16x16x64_i8(
                        af[u], bfv[v], acc[u][v], 0, 0, 0);
#pragma unroll
            for (int v = 0; v < 4; ++v) bfv[v] = bnx[v];
        }
        int pTile = (tBase + pt) * 128;
#pragma unroll
        for (int v = 0; v < 4; ++v) {
            int col  = pTile + wcol + 16 * v + j16;
            float pn = pnormS[col];
#pragma unroll
            for (int u = 0; u < 4; ++u)
#pragma unroll
                for (int rg = 0; rg < 4; ++rg) {
                    float sc   = pn - 2.f * (float)acc[u][v][rg];
                    int   slot = u * 4 + rg;
                    if (sc < bestv[slot]) { bestv[slot] = sc; besti[slot] = col; }
                }
        }
    }
    // reduce across the 16 col-lanes (same rows)
#pragma unroll
    for (int off = 1; off < 16; off <<= 1) {
#pragma unroll
        for (int s = 0; s < 16; ++s) {
            float ov = __shfl_xor(bestv[s], off);
            int   oi = __shfl_xor(besti[s], off);
            if (ov < bestv[s] || (ov == bestv[s] && oi < besti[s])) {
                bestv[s] = ov; besti[s] = oi;
            }
        }
    }
    // cross-wave (col halves) via LDS (reuse As, safe after barrier)
    __syncthreads();
    float* cv = (float*)As;
    int*   ci = ((int*)As) + 256;
    if (j16 == 0) {
#pragma unroll
        for (int u = 0; u < 4; ++u)
#pragma unroll
            for (int rg = 0; rg < 4; ++rg) {
                int row = wrow + 16 * u + 4 * q + rg;
                cv[(w & 1) * 128 + row] = bestv[u * 4 + rg];
                ci[(w & 1) * 128 + row] = besti[u * 4 + rg];
            }
    }
    __syncthreads();
    if (t < 128) {
        float v0 = cv[t];       int i0 = ci[t];
        float v1 = cv[128 + t]; int i1 = ci[128 + t];
        if (v1 < v0 || (v1 == v0 && i1 < i0)) { v0 = v1; i0 = i1; }
        minval[(size_t)blockIdx.y * B_SZ + rowBase + t] = v0;
        minidx[(size_t)blockIdx.y * B_SZ + rowBase + t] = i0;
    }
}

// ---------------------------------------------------------------------------
// Fused combine + gather + straight-through write + MSE partials.
// ---------------------------------------------------------------------------
__global__ __launch_bounds__(256) void gather_kernel(const float* __restrict__ sample,
                                                     const float* __restrict__ protos,
                                                     const float* __restrict__ minval,
                                                     const int* __restrict__ minidx,
                                                     float* __restrict__ out,
                                                     float* __restrict__ msepart)
{
    int t  = threadIdx.x;
    int rb = blockIdx.x * 8;
    __shared__ int sidx[8];
    if (t < 8) {
        int i = rb + t;
        float bv = minval[i];
        int   bi = minidx[i];
#pragma unroll
        for (int s = 1; s < SPLITS; ++s) {
            float v = minval[(size_t)s * B_SZ + i];
            int   j = minidx[(size_t)s * B_SZ + i];
            if (v < bv || (v == bv && j < bi)) { bv = v; bi = j; }
        }
        sidx[t] = bi;
    }
    __syncthreads();
    float part = 0.f;
#pragma unroll
    for (int u = 0; u < 8; ++u) {
        int i  = rb + u;
        int id = sidx[u];
        float qv = protos[(size_t)id * COMM + t];
        float s  = sample[(size_t)i * COMM + t];
        float d  = qv - s;
        out[(size_t)i * COMM + t] = s + d;
        part += d * d;
    }
#pragma unroll
    for (int off = 32; off; off >>= 1) part += __shfl_down(part, off);
    __shared__ float wsum[4];
    if ((t & 63) == 0) wsum[t >> 6] = part;
    __syncthreads();
    if (t == 0) msepart[blockIdx.x] = wsum[0] + wsum[1] + wsum[2] + wsum[3];
}

// ---------------------------------------------------------------------------
__global__ __launch_bounds__(256) void finalize_kernel(const float* __restrict__ klpart, int nkl,
                                                       const float* __restrict__ msepart, int nmse,
                                                       float* __restrict__ out)
{
    int t = threadIdx.x;
    double kl = 0.0, mse = 0.0;
    for (int i = t; i < nkl;  i += 256) kl  += (double)klpart[i];
    for (int i = t; i < nmse; i += 256) mse += (double)msepart[i];
#pragma unroll
    for (int off = 32; off; off >>= 1) {
        kl  += __shfl_down(kl, off);
        mse += __shfl_down(mse, off);
    }
    __shared__ double skl[4], smse[4];
    if ((t & 63) == 0) { skl[t >> 6] = kl; smse[t >> 6] = mse; }
    __syncthreads();
    if (t == 0) {
        double K  = skl[0] + skl[1] + skl[2] + skl[3];
        double M  = smse[0] + smse[1] + smse[2] + smse[3];
        double kld = -0.5 * K / (double)B_SZ;
        double vq  = 1.25 * M / ((double)B_SZ * (double)COMM);
        out[(size_t)B_SZ * COMM]     = (float)(kld + vq);
        out[(size_t)B_SZ * COMM + 1] = (float)kld;
    }
}

// ---------------------------------------------------------------------------
extern "C" void kernel_launch(void* const* d_in, const int* in_sizes, int n_in,
                              void* d_out, int out_size, void* d_ws, size_t ws_size,
                              hipStream_t stream)
{
    const float* x      = (const float*)d_in[0];
    const float* eps    = (const float*)d_in[1];
    const float* W_feat = (const float*)d_in[2];
    const float* b_feat = (const float*)d_in[3];
    const float* W0     = (const float*)d_in[4];
    const float* b0     = (const float*)d_in[5];
    const float* W1     = (const float*)d_in[6];
    const float* b1     = (const float*)d_in[7];
    const float* W_mu   = (const float*)d_in[8];
    const float* b_mu   = (const float*)d_in[9];
    const float* W_var  = (const float*)d_in[10];
    const float* b_var  = (const float*)d_in[11];
    const float* protos = (const float*)d_in[12];
    float* out = (float*)d_out;

    char* wsb = (char*)d_ws;
    size_t off = 0;
    auto alloc = [&](size_t bytes) -> void* {
        void* p = wsb + off;
        off = (off + bytes + 255) & ~(size_t)255;
        return p;
    };
    unsigned short* Wft     = (unsigned short*)alloc((size_t)IN_D * HID * 2);
    unsigned short* W0t     = (unsigned short*)alloc((size_t)HID * HID * 2);
    unsigned short* W1t     = (unsigned short*)alloc((size_t)HID * COMM * 2);
    unsigned short* Wmt     = (unsigned short*)alloc((size_t)COMM * COMM * 2);
    unsigned short* Wvt     = (unsigned short*)alloc((size_t)COMM * COMM * 2);
    unsigned short* h3b     = (unsigned short*)alloc((size_t)B_SZ * COMM * 2);
    float*          sample  = (float*)alloc((size_t)B_SZ * COMM * 4);
    char*           sampleq = (char*) alloc((size_t)B_SZ * COMM);
    char*           protoq  = (char*) alloc((size_t)NPROTO * COMM);
    float*          pnormS  = (float*)alloc((size_t)NPROTO * 4);
    float*          minval  = (float*)alloc((size_t)SPLITS * B_SZ * 4);
    int*            minidx  = (int*)  alloc((size_t)SPLITS * B_SZ * 4);
    float*          klpart  = (float*)alloc(1024 * 4);
    float*          msepart = (float*)alloc(4096 * 4);

    prep_all<<<2154, 256, 0, stream>>>(W_feat, W0, W1, W_mu, W_var, protos,
                                       Wft, W0t, W1t, Wmt, Wvt, pnormS, protoq);
    mlp_fused<<<B_SZ / 32, 256, 0, stream>>>(x, Wft, b_feat, W0t, b0, W1t, b1, h3b);
    head_mfma<<<B_SZ / 32, 256, 0, stream>>>(h3b, Wmt, b_mu, Wvt, b_var, eps,
                                             sample, sampleq, klpart);
    vq_argmin_i8<<<dim3(B_SZ / 128, SPLITS), 256, 0, stream>>>(sampleq, protoq, pnormS,
                                                               minval, minidx);
    gather_kernel<<<B_SZ / 8, 256, 0, stream>>>(sample, protos, minval, minidx,
                                                out, msepart);
    finalize_kernel<<<1, 256, 0, stream>>>(klpart, 1024, msepart, 4096, out);
}